// Round 2
// baseline (569.393 us; speedup 1.0000x reference)
//
#include <hip/hip_runtime.h>

#define NB 32  // batch size B (fixed by problem)

// ---------------------------------------------------------------------------
// x (B, N) -> xt (N, B): 32x32 LDS tile transpose, coalesced read and write.
// ---------------------------------------------------------------------------
__global__ void transpose_x_kernel(const float* __restrict__ x,
                                   float* __restrict__ xt, int N) {
    __shared__ float tile[32][33];
    int n0 = blockIdx.x * 32;
    for (int i = threadIdx.y; i < 32; i += 8) {
        int n = n0 + threadIdx.x;
        tile[i][threadIdx.x] = (n < N) ? x[(size_t)i * N + n] : 0.f;
    }
    __syncthreads();
    for (int i = threadIdx.y; i < 32; i += 8) {
        int n = n0 + i;
        if (n < N) xt[(size_t)n * NB + threadIdx.x] = tile[threadIdx.x][i];
    }
}

// ---------------------------------------------------------------------------
// Histogram of dst: count[m] = #edges with dst==m. Int atomics on 400 KB
// (L2-resident), 3.2M ops total.
// ---------------------------------------------------------------------------
__global__ void hist_kernel(const int* __restrict__ dst, int* __restrict__ count,
                            int nnz) {
    int i = blockIdx.x * blockDim.x + threadIdx.x;
    if (i < nnz) atomicAdd(&count[dst[i]], 1);
}

// ---------------------------------------------------------------------------
// Exclusive scan, level 1: 1024 elements/block (256 thr x 4), Hillis-Steele
// in LDS. Writes per-element exclusive offsets (block-local) + block sums.
// ---------------------------------------------------------------------------
__global__ void scan_block_kernel(const int* __restrict__ count,
                                  int* __restrict__ off,
                                  int* __restrict__ bsum, int M) {
    __shared__ int lds[256];
    int tid = threadIdx.x;
    int base = blockIdx.x * 1024 + tid * 4;
    int v[4], s = 0;
#pragma unroll
    for (int j = 0; j < 4; j++) {
        int idx = base + j;
        v[j] = (idx < M) ? count[idx] : 0;
        s += v[j];
    }
    lds[tid] = s;
    __syncthreads();
    for (int d = 1; d < 256; d <<= 1) {
        int t = (tid >= d) ? lds[tid - d] : 0;
        __syncthreads();
        lds[tid] += t;
        __syncthreads();
    }
    int ex = lds[tid] - s;  // exclusive prefix for this thread's chunk
#pragma unroll
    for (int j = 0; j < 4; j++) {
        int idx = base + j;
        if (idx < M) off[idx] = ex;
        ex += v[j];
    }
    if (tid == 255) bsum[blockIdx.x] = lds[255];
}

// Level 2: scan the (<=256) block sums in one block.
__global__ void scan_sums_kernel(const int* __restrict__ bsum,
                                 int* __restrict__ boff, int nb) {
    __shared__ int lds[256];
    int tid = threadIdx.x;
    int s = (tid < nb) ? bsum[tid] : 0;
    lds[tid] = s;
    __syncthreads();
    for (int d = 1; d < 256; d <<= 1) {
        int t = (tid >= d) ? lds[tid - d] : 0;
        __syncthreads();
        lds[tid] += t;
        __syncthreads();
    }
    if (tid < nb) boff[tid] = lds[tid] - s;
}

// Level 3: add block offsets; also init the bin cursors.
__global__ void scan_add_kernel(int* __restrict__ off,
                                const int* __restrict__ boff,
                                int* __restrict__ cursor, int M) {
    int i = blockIdx.x * blockDim.x + threadIdx.x;
    if (i < M) {
        int o = off[i] + boff[i >> 10];
        off[i] = o;
        cursor[i] = o;
    }
}

// ---------------------------------------------------------------------------
// Scatter edges into dst-sorted bins. One packed 8B record per edge
// (src, val bits) so the gather loop does a single load per edge.
// ---------------------------------------------------------------------------
__global__ void bin_kernel(const int* __restrict__ src,
                           const int* __restrict__ dst,
                           const float* __restrict__ vals,
                           int* __restrict__ cursor,
                           int2* __restrict__ bedge, int nnz) {
    int i = blockIdx.x * blockDim.x + threadIdx.x;
    if (i < nnz) {
        int d = dst[i];
        int p = atomicAdd(&cursor[d], 1);
        bedge[p] = make_int2(src[i], __float_as_int(vals[i]));
    }
}

// ---------------------------------------------------------------------------
// One wave per output node m (4 waves/block, 8 m's per wave => 32 m's/block).
// Lanes: b = lane&31 is the batch, half = lane>>5 strides the edge list.
// 2x unroll => 4 independent xt gathers in flight per wave.
// Results staged in a 32x32 LDS tile, written to out (B, M) coalesced +bias.
// ---------------------------------------------------------------------------
__global__ void gather_kernel(const int2* __restrict__ bedge,
                              const int* __restrict__ off,
                              const int* __restrict__ count,
                              const float* __restrict__ xt,
                              const float* __restrict__ bias,
                              float* __restrict__ out, int M) {
    __shared__ float tile[32][33];
    int lane = threadIdx.x & 63;
    int w = threadIdx.x >> 6;
    int half = lane >> 5;
    int b = lane & 31;
    int m0 = blockIdx.x * 32;

    for (int k = 0; k < 8; k++) {
        int mloc = w * 8 + k;
        int m = m0 + mloc;
        float acc0 = 0.f, acc1 = 0.f;
        if (m < M) {
            int n = count[m];
            int o = off[m];
            int i = half;
            for (; i + 2 < n; i += 4) {
                int2 e0 = bedge[o + i];
                int2 e1 = bedge[o + i + 2];
                acc0 += __int_as_float(e0.y) * xt[(size_t)e0.x * NB + b];
                acc1 += __int_as_float(e1.y) * xt[(size_t)e1.x * NB + b];
            }
            for (; i < n; i += 2) {
                int2 e = bedge[o + i];
                acc0 += __int_as_float(e.y) * xt[(size_t)e.x * NB + b];
            }
        }
        float acc = acc0 + acc1;
        acc += __shfl_xor(acc, 32, 64);  // combine the two halves
        if (lane < 32) tile[lane][mloc] = acc;  // tile[b][mloc], conflict-free
    }
    __syncthreads();

    // 256 threads x 4 floats = 1024 outputs (32 b x 32 m), float4 stores.
    int b2 = threadIdx.x >> 3;
    int j0 = (threadIdx.x & 7) * 4;
    int m = m0 + j0;
    if (m + 3 < M) {
        float4 bv = *(const float4*)&bias[m];
        float4 o4;
        o4.x = tile[b2][j0 + 0] + bv.x;
        o4.y = tile[b2][j0 + 1] + bv.y;
        o4.z = tile[b2][j0 + 2] + bv.z;
        o4.w = tile[b2][j0 + 3] + bv.w;
        *(float4*)&out[(size_t)b2 * M + m] = o4;
    } else {
        for (int j = 0; j < 4; j++)
            if (m + j < M)
                out[(size_t)b2 * M + m + j] = tile[b2][j0 + j] + bias[m + j];
    }
}

extern "C" void kernel_launch(void* const* d_in, const int* in_sizes, int n_in,
                              void* d_out, int out_size, void* d_ws, size_t ws_size,
                              hipStream_t stream) {
    const float* x       = (const float*)d_in[0];   // (B, N, 1) fp32
    const int*   indices = (const int*)  d_in[1];   // (2, NNZ) int32
    const float* vals    = (const float*)d_in[2];   // (NNZ,) fp32
    const float* bias    = (const float*)d_in[3];   // (M, 1) fp32
    float* out = (float*)d_out;                     // (B, M, 1) fp32

    int nnz = in_sizes[1] / 2;
    int N   = in_sizes[0] / NB;
    int M   = in_sizes[3];

    const int* src = indices;
    const int* dst = indices + nnz;

    // workspace layout (all 4B-granular; bedge offset is 8B-aligned)
    float* xt     = (float*)d_ws;                 // N*32 floats
    int*   count  = (int*)(xt + (size_t)N * NB);  // M
    int*   off    = count + M;                    // M
    int*   cursor = off + M;                      // M
    int*   bsum   = cursor + M;                   // 256
    int*   boff   = bsum + 256;                   // 256
    int2*  bedge  = (int2*)(boff + 256);          // nnz int2

    hipMemsetAsync(count, 0, (size_t)M * sizeof(int), stream);

    transpose_x_kernel<<<(N + 31) / 32, dim3(32, 8), 0, stream>>>(x, xt, N);

    int egrid = (nnz + 255) / 256;
    hist_kernel<<<egrid, 256, 0, stream>>>(dst, count, nnz);

    int nb = (M + 1023) / 1024;  // 98 for M=100000 (must be <= 256)
    scan_block_kernel<<<nb, 256, 0, stream>>>(count, off, bsum, M);
    scan_sums_kernel<<<1, 256, 0, stream>>>(bsum, boff, nb);
    scan_add_kernel<<<(M + 255) / 256, 256, 0, stream>>>(off, boff, cursor, M);

    bin_kernel<<<egrid, 256, 0, stream>>>(src, dst, vals, cursor, bedge, nnz);

    gather_kernel<<<(M + 31) / 32, 256, 0, stream>>>(bedge, off, count, xt, bias,
                                                     out, M);
}